// Round 1
// baseline (50.044 us; speedup 1.0000x reference)
//
#include <hip/hip_runtime.h>
#include <hip/hip_bf16.h>

typedef _Float16 half8 __attribute__((ext_vector_type(8)));
typedef float f32x4 __attribute__((ext_vector_type(4)));

#define N_U      4096
#define N_L      65536
#define NZ       32
#define BM       256      // U rows per block
#define UT_PER_WAVE 4     // 16-col u-tiles per wave (4 waves -> 256 rows)
#define NSPLIT   64       // L splits (grid.x)
#define LSLICE   (N_L / NSPLIT)   // 1024 L rows per block
#define LCHUNK   256      // L rows staged per phase
#define LDS_STRIDE 80     // bytes per staged L row: 64B f16 data + 16B pad

// ---------------------------------------------------------------------------
// Order-preserving float <-> uint key (works for negative values too)
__device__ __forceinline__ unsigned int f2key(float f) {
    unsigned int u = __float_as_uint(f);
    return (u & 0x80000000u) ? ~u : (u | 0x80000000u);
}
__device__ __forceinline__ float key2f(unsigned int k) {
    unsigned int u = (k & 0x80000000u) ? (k & 0x7FFFFFFFu) : ~k;
    return __uint_as_float(u);
}

// ---------------------------------------------------------------------------
__global__ __launch_bounds__(256) void kInit(unsigned int* __restrict__ outkey,
                                             unsigned int* __restrict__ ws) {
    int i = blockIdx.x * 256 + threadIdx.x;
    if (i < N_U) outkey[i] = 0xFFFFFFFFu;   // max key == +inf-ish
    if (i == 0) { ws[0] = 0u;               // running max of dd (dd>0 -> uint order ok)
                  ws[1] = 0x7F800000u; }    // running min of dd, init +INF bits
}

// ---------------------------------------------------------------------------
// Heavy kernel: per (L-split, U-block), min over L-slice of (||l||^2 - 2 u.l)
__global__ __launch_bounds__(256) void kA(const float* __restrict__ Uz,
                                          const float* __restrict__ Lz,
                                          unsigned int* __restrict__ outkey) {
    __shared__ __align__(16) unsigned char smem[LCHUNK * LDS_STRIDE + LCHUNK * 4];
    float* lsq = (float*)(smem + LCHUNK * LDS_STRIDE);

    const int tid  = threadIdx.x;
    const int lane = tid & 63;
    const int wave = tid >> 6;
    const int g    = lane >> 4;    // lane group 0..3  -> k = g*8 + e (our chosen perm)
    const int lc   = lane & 15;    // col within tile

    const int ubase = blockIdx.y * BM;
    const int lbase = blockIdx.x * LSLICE;

    // U B-fragments: lane holds U[ubase + tile*16 + lc][g*8 .. g*8+7] as f16
    half8 bfrag[UT_PER_WAVE];
#pragma unroll
    for (int t = 0; t < UT_PER_WAVE; ++t) {
        int urow = ubase + (wave * UT_PER_WAVE + t) * 16 + lc;
        const f32x4* p = (const f32x4*)(Uz + (size_t)urow * NZ + g * 8);
        f32x4 a = p[0], b = p[1];
        bfrag[t] = (half8){(_Float16)a[0], (_Float16)a[1], (_Float16)a[2], (_Float16)a[3],
                           (_Float16)b[0], (_Float16)b[1], (_Float16)b[2], (_Float16)b[3]};
    }

    float minv[UT_PER_WAVE];
#pragma unroll
    for (int t = 0; t < UT_PER_WAVE; ++t) minv[t] = INFINITY;

    for (int ph = 0; ph < LSLICE / LCHUNK; ++ph) {
        __syncthreads();
        // ---- stage LCHUNK L rows: f32 -> f16 row-major (stride 80B) + row norms
        {
            const float* src = Lz + (size_t)(lbase + ph * LCHUNK + tid) * NZ;
            unsigned char* dst = smem + tid * LDS_STRIDE;
            float s = 0.f;
#pragma unroll
            for (int j = 0; j < 4; ++j) {
                f32x4 a = ((const f32x4*)src)[2 * j];
                f32x4 b = ((const f32x4*)src)[2 * j + 1];
                s = fmaf(a[0], a[0], s); s = fmaf(a[1], a[1], s);
                s = fmaf(a[2], a[2], s); s = fmaf(a[3], a[3], s);
                s = fmaf(b[0], b[0], s); s = fmaf(b[1], b[1], s);
                s = fmaf(b[2], b[2], s); s = fmaf(b[3], b[3], s);
                half8 h = (half8){(_Float16)a[0], (_Float16)a[1], (_Float16)a[2], (_Float16)a[3],
                                  (_Float16)b[0], (_Float16)b[1], (_Float16)b[2], (_Float16)b[3]};
                *(half8*)(dst + j * 16) = h;
            }
            lsq[tid] = s;
        }
        __syncthreads();
        // ---- compute: 16 L-tiles x 4 U-tiles MFMAs
#pragma unroll 4
        for (int lt = 0; lt < LCHUNK / 16; ++lt) {
            half8 afrag = *(const half8*)(smem + (lt * 16 + lc) * LDS_STRIDE + g * 16);
            f32x4 l4 = *(const f32x4*)(lsq + lt * 16 + g * 4);
#pragma unroll
            for (int t = 0; t < UT_PER_WAVE; ++t) {
                f32x4 acc = (f32x4){0.f, 0.f, 0.f, 0.f};
                acc = __builtin_amdgcn_mfma_f32_16x16x32_f16(afrag, bfrag[t], acc, 0, 0, 0);
                float c0 = fmaf(-2.f, acc[0], l4[0]);
                float c1 = fmaf(-2.f, acc[1], l4[1]);
                float c2 = fmaf(-2.f, acc[2], l4[2]);
                float c3 = fmaf(-2.f, acc[3], l4[3]);
                minv[t] = fminf(minv[t], fminf(fminf(c0, c1), fminf(c2, c3)));
            }
        }
    }

    // ---- reduce across lane groups (rows) and publish
#pragma unroll
    for (int t = 0; t < UT_PER_WAVE; ++t) {
        float v = minv[t];
        v = fminf(v, __shfl_xor(v, 16));
        v = fminf(v, __shfl_xor(v, 32));
        if (g == 0) {
            int ucol = ubase + (wave * UT_PER_WAVE + t) * 16 + lc;
            atomicMin(&outkey[ucol], f2key(v));
        }
    }
}

// ---------------------------------------------------------------------------
// Per-row epilogue: invert key, add ||u||^2, sqrt, dens, dd; global min/max
__global__ __launch_bounds__(256) void kB(const float* __restrict__ Uz,
                                          float* __restrict__ out,
                                          unsigned int* __restrict__ ws) {
    int u = blockIdx.x * 256 + threadIdx.x;
    unsigned int key = ((const unsigned int*)out)[u];
    float minq = key2f(key);                       // min_j (||l||^2 - 2 u.l)

    const f32x4* p = (const f32x4*)(Uz + (size_t)u * NZ);
    float s = 0.f;
#pragma unroll
    for (int j = 0; j < 8; ++j) {
        f32x4 v = p[j];
        s = fmaf(v[0], v[0], s); s = fmaf(v[1], v[1], s);
        s = fmaf(v[2], v[2], s); s = fmaf(v[3], v[3], s);
    }
    float sq  = s + minq;                          // ||u||^2 + min_j(...)
    float div = sqrtf(fmaxf(sq, 0.f));
    float dens = -0.5f * s - 29.406033062549525f;  // -0.5*||u||^2 - 16*log(2pi)
    float dd = expf(dens) * (div + 1e-18f);
    out[u] = dd;
    unsigned int b = __float_as_uint(dd);          // dd > 0 -> uint order == float order
    atomicMax(&ws[0], b);
    atomicMin(&ws[1], b);
}

// ---------------------------------------------------------------------------
__global__ __launch_bounds__(256) void kC(float* __restrict__ out,
                                          const unsigned int* __restrict__ ws) {
    int u = blockIdx.x * 256 + threadIdx.x;
    float mx = __uint_as_float(ws[0]);
    float mn = __uint_as_float(ws[1]);
    float dd = out[u];
    out[u] = (dd - mn) / ((mx - mn) + 1e-18f);
}

// ---------------------------------------------------------------------------
extern "C" void kernel_launch(void* const* d_in, const int* in_sizes, int n_in,
                              void* d_out, int out_size, void* d_ws, size_t ws_size,
                              hipStream_t stream) {
    const float* Uz = (const float*)d_in[1];
    const float* Lz = (const float*)d_in[2];
    float* out = (float*)d_out;
    unsigned int* ws = (unsigned int*)d_ws;

    kInit<<<(N_U + 255) / 256, 256, 0, stream>>>((unsigned int*)d_out, ws);
    dim3 grid(NSPLIT, N_U / BM);   // 64 x 16 = 1024 blocks
    kA<<<grid, 256, 0, stream>>>(Uz, Lz, (unsigned int*)d_out);
    kB<<<N_U / 256, 256, 0, stream>>>(Uz, out, ws);
    kC<<<N_U / 256, 256, 0, stream>>>(out, ws);
}